// Round 1
// baseline (641.327 us; speedup 1.0000x reference)
//
#include <hip/hip_runtime.h>
#include <math.h>

namespace {
constexpr int Vv  = 50257;
constexpr int Dc  = 128;
constexpr int Kc  = 3;
constexpr int NBc = 8;
constexpr int Jc  = 24;      // K*NB
constexpr int Tc  = 64;
constexpr int CHV = 1024;                      // vocab elems per block chunk
constexpr int NCH = (Vv + CHV - 1) / CHV;      // 50
constexpr float INV_SQRT_D = 0.08838834764831845f;
constexpr float DIVW = 2.0f;

// ws layout (float offsets)
constexpr size_t WS_PSI  = 0;        // 24*128
constexpr size_t WS_G    = 4096;     // 24*24
constexpr size_t WS_WALL = 8192;     // 64*24
constexpr size_t WS_PART = 12288;    // 64*50*9 = 28800
constexpr size_t WS_LOGZ = 45056;    // 64*4
constexpr size_t WS_P2T  = 65536;    // 24*V  (transposed: [j][v] for coalescing)

// out layout (float offsets), reference return order
constexpr size_t OFF_TOK = 0;
constexpr size_t OFF_RHO = (size_t)Tc * Vv;
constexpr size_t OFF_S   = OFF_RHO + (size_t)Tc * Dc * Dc;
constexpr size_t OFF_H   = OFF_S + Tc;
constexpr size_t OFF_F   = OFF_H + Tc;
constexpr size_t OFF_PF  = OFF_F + Tc;
}

// online-softmax merge helpers
__device__ __forceinline__ void comb(float& m1, float& s1, float m2, float s2) {
  float M = fmaxf(m1, m2);
  float e1 = (s1 > 0.f) ? expf(m1 - M) : 0.f;
  float e2 = (s2 > 0.f) ? expf(m2 - M) : 0.f;
  s1 = s1 * e1 + s2 * e2;
  m1 = M;
}
__device__ __forceinline__ void comb_sl(float& m1, float& s1, float& sl1,
                                        float m2, float s2, float sl2) {
  float M = fmaxf(m1, m2);
  float e1 = (s1 > 0.f) ? expf(m1 - M) : 0.f;
  float e2 = (s2 > 0.f) ? expf(m2 - M) : 0.f;
  s1 = s1 * e1 + s2 * e2;
  sl1 = sl1 * e1 + sl2 * e2;
  m1 = M;
}

// ---------- psi (normalized bubbles) + Gram matrix G = Psi^T Psi ----------
__global__ void k_prep(const float* __restrict__ bub, float* __restrict__ ws) {
  __shared__ float psi[Jc * Dc];
  __shared__ float nrm[Jc];
  int tid = threadIdx.x;
  for (int i = tid; i < Jc * Dc; i += 256) psi[i] = bub[i];
  __syncthreads();
  if (tid < Jc) {
    float s = 0.f;
    for (int d = 0; d < Dc; ++d) { float b = psi[tid * Dc + d]; s += b * b; }
    nrm[tid] = sqrtf(s) + 1e-10f;
  }
  __syncthreads();
  for (int i = tid; i < Jc * Dc; i += 256) {
    float v = psi[i] / nrm[i / Dc];
    psi[i] = v;
    ws[WS_PSI + i] = v;
  }
  __syncthreads();
  for (int i = tid; i < Jc * Jc; i += 256) {
    int r = i / Jc, c = i % Jc;
    float s = 0.f;
    for (int d = 0; d < Dc; ++d) s += psi[r * Dc + d] * psi[c * Dc + d];
    ws[WS_G + i] = s;
  }
}

// ---------- P2T[j][v] = (E[v] . psi_j)^2 ----------
__global__ void k_proj(const float* __restrict__ E, float* __restrict__ ws) {
  __shared__ float4 psi4[Jc][Dc / 4];
  int tid = threadIdx.x;
  for (int i = tid; i < Jc * Dc / 4; i += 256)
    ((float4*)psi4)[i] = ((const float4*)(ws + WS_PSI))[i];
  __syncthreads();
  int v = blockIdx.x * 256 + tid;
  if (v >= Vv) return;
  float acc[Jc];
#pragma unroll
  for (int j = 0; j < Jc; ++j) acc[j] = 0.f;
  const float4* e4 = (const float4*)(E + (size_t)v * Dc);
  for (int d = 0; d < Dc / 4; ++d) {
    float4 e = e4[d];
#pragma unroll
    for (int j = 0; j < Jc; ++j) {
      float4 p = psi4[j][d];
      acc[j] += e.x * p.x + e.y * p.y + e.z * p.z + e.w * p.w;
    }
  }
#pragma unroll
  for (int j = 0; j < Jc; ++j) ws[WS_P2T + (size_t)j * Vv + v] = acc[j] * acc[j];
}

// ---------- sequential recurrence over T=64 steps; emits w[t][24] ----------
__global__ void k_recur(const int* __restrict__ tok, const float* __restrict__ E,
                        const float* __restrict__ bub, const float* __restrict__ pdb,
                        const float* __restrict__ psn, float* __restrict__ ws) {
  __shared__ float mem[Kc * NBc * Dc];
  __shared__ float x[Dc];
  __shared__ float mm[Kc * Dc];
  __shared__ float xm[Kc * Dc];
  __shared__ float sc[Jc];
  __shared__ float wsm[Jc];
  __shared__ float dec[Kc];
  __shared__ float red[8];   // [0..2]=dot(mm,x), [3..5]=|mm|^2, [6]=|x|^2
  int tid = threadIdx.x;
  float db = pdb[0];
  float sens = fabsf(psn[0]);
  for (int i = tid; i < Kc * NBc * Dc; i += 256) mem[i] = 0.f;
  __syncthreads();
  for (int t = 0; t < Tc; ++t) {
    int tk = tok[t];
    if (tid < Dc) x[tid] = E[(size_t)tk * Dc + tid];
    for (int i = tid; i < Kc * Dc; i += 256) {
      int k = i / Dc, d = i % Dc;
      float s = 0.f;
#pragma unroll
      for (int n = 0; n < NBc; ++n) s += mem[(k * NBc + n) * Dc + d];
      mm[i] = s * (1.f / NBc);
    }
    __syncthreads();
    {
      int wv = tid >> 6, ln = tid & 63;
      float a, b = 0.f;
      if (wv < Kc) {
        float m1 = mm[wv * Dc + ln], m2 = mm[wv * Dc + 64 + ln];
        float x1 = x[ln], x2 = x[64 + ln];
        a = m1 * x1 + m2 * x2;
        b = m1 * m1 + m2 * m2;
      } else {
        float x1 = x[ln], x2 = x[64 + ln];
        a = x1 * x1 + x2 * x2;
      }
#pragma unroll
      for (int off = 32; off; off >>= 1) { a += __shfl_down(a, off); b += __shfl_down(b, off); }
      if (ln == 0) { if (wv < Kc) { red[wv] = a; red[3 + wv] = b; } else red[6] = a; }
    }
    __syncthreads();
    if (tid < Kc) {
      float mn = sqrtf(red[3 + tid]) + 1e-10f;
      float xn = sqrtf(red[6]) + 1e-10f;
      float cosv = red[tid] / (xn * mn);
      float nov = (mn > 1e-8f) ? (1.f - cosv) : 1.f;
      dec[tid] = 1.f / (1.f + expf(-(db - sens * nov)));
    }
    __syncthreads();
    for (int i = tid; i < Kc * Dc; i += 256) xm[i] = x[i % Dc] + dec[i / Dc] * mm[i];
    __syncthreads();
    if (tid < Jc * 8) {           // j = tid/8 (24 dots), c = tid%8 covers 16 dims each
      int j = tid >> 3, c = tid & 7;
      int k = j >> 3;
      float s = 0.f;
#pragma unroll
      for (int q = 0; q < 16; ++q) { int d = c * 16 + q; s += bub[j * Dc + d] * xm[k * Dc + d]; }
      s += __shfl_down(s, 4);
      s += __shfl_down(s, 2);
      s += __shfl_down(s, 1);
      if (c == 0) sc[j] = s * (DIVW * INV_SQRT_D);
    }
    __syncthreads();
    if (tid < Kc) {
      float mx = sc[tid * NBc];
#pragma unroll
      for (int n = 1; n < NBc; ++n) mx = fmaxf(mx, sc[tid * NBc + n]);
      float e[NBc]; float ss = 0.f;
#pragma unroll
      for (int n = 0; n < NBc; ++n) { e[n] = expf(sc[tid * NBc + n] - mx); ss += e[n]; }
#pragma unroll
      for (int n = 0; n < NBc; ++n) wsm[tid * NBc + n] = e[n] / ss;
    }
    __syncthreads();
    if (tid < Jc) ws[WS_WALL + (size_t)t * Jc + tid] = wsm[tid];
    for (int i = tid; i < Kc * NBc * Dc; i += 256) {
      int kn = i / Dc, d = i % Dc;
      int k = kn >> 3;
      float de = dec[k];
      float wv2 = wsm[kn];
      float eq = wv2 * xm[k * Dc + d] + (1.f - wv2) * bub[i];
      mem[i] = de * mem[i] + (1.f - de) * eq;
    }
    __syncthreads();
  }
}

// ---------- rho[t] = sum_j (w_j/3) psi_j psi_j^T  (one block per t) ----------
__global__ void k_rho(const float* __restrict__ ws, float* __restrict__ out) {
  int t = blockIdx.x;
  __shared__ float psis[Jc * Dc];
  __shared__ float wsh[Jc];
  int tid = threadIdx.x;
  for (int i = tid; i < Jc * Dc; i += 256) psis[i] = ws[WS_PSI + i];
  if (tid < Jc) wsh[tid] = ws[WS_WALL + (size_t)t * Jc + tid] * (1.f / 3.f);
  __syncthreads();
  int d = tid >> 1, eh = (tid & 1) * 64;
  float4 acc[16];
#pragma unroll
  for (int i = 0; i < 16; ++i) acc[i] = make_float4(0.f, 0.f, 0.f, 0.f);
  for (int j = 0; j < Jc; ++j) {
    float a = wsh[j] * psis[j * Dc + d];
    const float4* pr = (const float4*)&psis[j * Dc + eh];
#pragma unroll
    for (int i = 0; i < 16; ++i) {
      float4 p = pr[i];
      acc[i].x += a * p.x; acc[i].y += a * p.y; acc[i].z += a * p.z; acc[i].w += a * p.w;
    }
  }
  float* o = out + OFF_RHO + (size_t)t * Dc * Dc + (size_t)d * Dc + eh;
#pragma unroll
  for (int i = 0; i < 16; ++i) ((float4*)o)[i] = acc[i];
}

// ---------- S_rho[t] via 24x24 Jacobi on M = D^1/2 G D^1/2 (wave per t) ----------
__global__ void k_eig(const float* __restrict__ ws, float* __restrict__ out) {
  int t = blockIdx.x;
  __shared__ float A[2][Jc * Jc];
  __shared__ float cA[Jc], cB[Jc];
  __shared__ int mate[Jc];
  int tid = threadIdx.x;   // 64 threads
  for (int i = tid; i < Jc * Jc; i += 64) {
    int r = i / Jc, c = i % Jc;
    A[0][i] = ws[WS_G + i] *
              sqrtf(ws[WS_WALL + (size_t)t * Jc + r] * ws[WS_WALL + (size_t)t * Jc + c]) *
              (1.f / 3.f);
  }
  __syncthreads();
  int cur = 0;
  for (int sweep = 0; sweep < 7; ++sweep) {
    for (int r = 0; r < 23; ++r) {
      if (tid < 12) {   // round-robin pairing: 12 disjoint pairs
        int p, q;
        if (tid == 0) { p = 23; q = r % 23; }
        else { p = (r + tid) % 23; q = (r - tid + 23) % 23; }
        float app = A[cur][p * Jc + p], aqq = A[cur][q * Jc + q], apq = A[cur][p * Jc + q];
        float c, s;
        if (fabsf(apq) < 1e-20f) { c = 1.f; s = 0.f; }
        else {
          float th = (aqq - app) / (2.f * apq);
          float tt = 1.f / (fabsf(th) + sqrtf(1.f + th * th));
          if (th < 0.f) tt = -tt;
          c = 1.f / sqrtf(1.f + tt * tt);
          s = tt * c;
        }
        mate[p] = q; mate[q] = p;
        cA[p] = c; cB[p] = -s;
        cA[q] = c; cB[q] = s;
      }
      __syncthreads();
      int nxt = cur ^ 1;
      for (int i = tid; i < Jc * Jc; i += 64) {
        int ri = i / Jc, ci = i % Jc;
        int rm = mate[ri], cm = mate[ci];
        A[nxt][i] = cA[ri] * cA[ci] * A[cur][ri * Jc + ci]
                  + cA[ri] * cB[ci] * A[cur][ri * Jc + cm]
                  + cB[ri] * cA[ci] * A[cur][rm * Jc + ci]
                  + cB[ri] * cB[ci] * A[cur][rm * Jc + cm];
      }
      cur = nxt;
      __syncthreads();
    }
  }
  // entropy of {diag(A)} U {104 x 1e-12 clipped zeros}
  float lam = 0.f;
  if (tid < Jc) lam = fmaxf(A[cur][tid * Jc + tid], 1e-12f);
  float tot = lam;
#pragma unroll
  for (int off = 32; off; off >>= 1) tot += __shfl_down(tot, off);
  tot = __shfl(tot, 0);
  tot += (float)(Dc - Jc) * 1e-12f;
  float term = 0.f;
  if (tid < Jc) { float p = lam / tot; term = p * logf(p); }
#pragma unroll
  for (int off = 32; off; off >>= 1) term += __shfl_down(term, off);
  if (tid == 0) {
    float pe = 1e-12f / tot;
    out[OFF_S + t] = -(term + (float)(Dc - Jc) * pe * logf(pe));
  }
}

// ---------- logits (stored into d_out prob regions) + online-softmax partials ----------
__global__ void k_logits(float* __restrict__ ws, float* __restrict__ out) {
  int ch = blockIdx.x, t = blockIdx.y, tid = threadIdx.x;
  __shared__ float wsh[Jc];
  __shared__ float rm[4][4], rs[4][4], rsl2[4];
  if (tid < Jc) wsh[tid] = ws[WS_WALL + (size_t)t * Jc + tid];
  __syncthreads();
  float m[4] = {-INFINITY, -INFINITY, -INFINITY, -INFINITY};
  float s[4] = {0.f, 0.f, 0.f, 0.f};
  float sl = 0.f;
  const float* p2 = ws + WS_P2T;
  for (int r = 0; r < 4; ++r) {
    int v = ch * CHV + r * 256 + tid;
    if (v >= Vv) break;
    float l0 = 0.f, l1 = 0.f, l2 = 0.f;
#pragma unroll
    for (int n = 0; n < NBc; ++n) {
      l0 += wsh[n]      * p2[(size_t)n * Vv + v];
      l1 += wsh[8 + n]  * p2[(size_t)(8 + n) * Vv + v];
      l2 += wsh[16 + n] * p2[(size_t)(16 + n) * Vv + v];
    }
    float l[4] = { l0, l1, l2, (l0 + l1 + l2) * (1.f / 3.f) };
    out[OFF_TOK + (size_t)t * Vv + v] = l[3];
    out[OFF_PF + ((size_t)t * Kc + 0) * Vv + v] = l0;
    out[OFF_PF + ((size_t)t * Kc + 1) * Vv + v] = l1;
    out[OFF_PF + ((size_t)t * Kc + 2) * Vv + v] = l2;
#pragma unroll
    for (int d = 0; d < 4; ++d) {
      float li = l[d];
      if (li > m[d]) {
        float e = expf(m[d] - li);       // 0 when m = -inf
        s[d] = s[d] * e + 1.f;
        if (d == 3) sl = sl * e + li;
        m[d] = li;
      } else {
        float e = expf(li - m[d]);
        s[d] += e;
        if (d == 3) sl += e * li;
      }
    }
  }
  // wave reduce
#pragma unroll
  for (int off = 32; off; off >>= 1) {
#pragma unroll
    for (int d = 0; d < 3; ++d) {
      float om = __shfl_down(m[d], off);
      float os = __shfl_down(s[d], off);
      comb(m[d], s[d], om, os);
    }
    float om = __shfl_down(m[3], off);
    float os = __shfl_down(s[3], off);
    float osl = __shfl_down(sl, off);
    comb_sl(m[3], s[3], sl, om, os, osl);
  }
  int wv = tid >> 6, ln = tid & 63;
  if (ln == 0) {
#pragma unroll
    for (int d = 0; d < 4; ++d) { rm[wv][d] = m[d]; rs[wv][d] = s[d]; }
    rsl2[wv] = sl;
  }
  __syncthreads();
  if (tid == 0) {
    float* part = ws + WS_PART + ((size_t)t * NCH + ch) * 9;
    for (int d = 0; d < 3; ++d) {
      float M = rm[0][d], S = rs[0][d];
      for (int w2 = 1; w2 < 4; ++w2) comb(M, S, rm[w2][d], rs[w2][d]);
      part[d] = M; part[4 + d] = S;
    }
    float M = rm[0][3], S = rs[0][3], SL = rsl2[0];
    for (int w2 = 1; w2 < 4; ++w2) comb_sl(M, S, SL, rm[w2][3], rs[w2][3], rsl2[w2]);
    part[3] = M; part[7] = S; part[8] = SL;
  }
}

// ---------- merge chunk partials -> logZ[t][4]; H, F ----------
__global__ void k_reduce(float* __restrict__ ws, float* __restrict__ out) {
  int t = blockIdx.x, tid = threadIdx.x;
  if (tid < 4) {
    float M = -INFINITY, S = 0.f, SL = 0.f;
    for (int ch = 0; ch < NCH; ++ch) {
      const float* p = ws + WS_PART + ((size_t)t * NCH + ch) * 9;
      if (tid == 3) comb_sl(M, S, SL, p[3], p[7], p[8]);
      else          comb(M, S, p[tid], p[4 + tid]);
    }
    float lz = M + logf(S);
    ws[WS_LOGZ + (size_t)t * 4 + tid] = lz;
    if (tid == 3) {
      float H = lz - SL / S;
      float Srho = out[OFF_S + t];
      out[OFF_H + t] = H;
      out[OFF_F + t] = H - Srho;
    }
  }
}

// ---------- in-place logits -> probs ----------
__global__ void k_norm(const float* __restrict__ ws, float* __restrict__ out, int foam) {
  int row = blockIdx.y, ch = blockIdx.x, tid = threadIdx.x;
  size_t base; int lzi;
  if (foam) { int t = row / Kc, k = row % Kc; base = OFF_PF + (size_t)row * Vv; lzi = t * 4 + k; }
  else { base = OFF_TOK + (size_t)row * Vv; lzi = row * 4 + 3; }
  float lz = ws[WS_LOGZ + lzi];
  for (int r = 0; r < 4; ++r) {
    int v = ch * CHV + r * 256 + tid;
    if (v < Vv) out[base + v] = expf(out[base + v] - lz);
  }
}

extern "C" void kernel_launch(void* const* d_in, const int* in_sizes, int n_in,
                              void* d_out, int out_size, void* d_ws, size_t ws_size,
                              hipStream_t stream) {
  const int*   tokens = (const int*)d_in[0];
  const float* E      = (const float*)d_in[1];
  const float* bub    = (const float*)d_in[2];
  const float* pdb    = (const float*)d_in[3];
  const float* psn    = (const float*)d_in[4];
  float* out = (float*)d_out;
  float* ws  = (float*)d_ws;

  k_prep<<<1, 256, 0, stream>>>(bub, ws);
  k_proj<<<(Vv + 255) / 256, 256, 0, stream>>>(E, ws);
  k_recur<<<1, 256, 0, stream>>>(tokens, E, bub, pdb, psn, ws);
  k_rho<<<Tc, 256, 0, stream>>>(ws, out);
  k_eig<<<Tc, 64, 0, stream>>>(ws, out);
  k_logits<<<dim3(NCH, Tc), 256, 0, stream>>>(ws, out);
  k_reduce<<<Tc, 64, 0, stream>>>(ws, out);
  k_norm<<<dim3(NCH, Tc), 256, 0, stream>>>(ws, out, 0);
  k_norm<<<dim3(NCH, Tc * Kc), 256, 0, stream>>>(ws, out, 1);
}

// Round 2
// 548.164 us; speedup vs baseline: 1.1700x; 1.1700x over previous
//
#include <hip/hip_runtime.h>
#include <math.h>

namespace {
constexpr int Vv  = 50257;
constexpr int Dc  = 128;
constexpr int Kc  = 3;
constexpr int NBc = 8;
constexpr int Jc  = 24;      // K*NB
constexpr int Tc  = 64;
constexpr int CHV = 1024;                      // vocab elems per block chunk
constexpr int NCH = (Vv + CHV - 1) / CHV;      // 50
constexpr float INV_SQRT_D = 0.08838834764831845f;
constexpr float DIVW = 2.0f;

// ws layout (float offsets)
constexpr size_t WS_PSI  = 0;        // 24*128
constexpr size_t WS_G    = 4096;     // 24*24
constexpr size_t WS_WALL = 8192;     // 64*24
constexpr size_t WS_PART = 12288;    // 64*50*9 = 28800
constexpr size_t WS_LOGZ = 45056;    // 64*4
constexpr size_t WS_P2T  = 65536;    // 24*V  (transposed: [j][v] for coalescing)

// out layout (float offsets), reference return order
constexpr size_t OFF_TOK = 0;
constexpr size_t OFF_RHO = (size_t)Tc * Vv;
constexpr size_t OFF_S   = OFF_RHO + (size_t)Tc * Dc * Dc;
constexpr size_t OFF_H   = OFF_S + Tc;
constexpr size_t OFF_F   = OFF_H + Tc;
constexpr size_t OFF_PF  = OFF_F + Tc;
}

// online-softmax merge helpers
__device__ __forceinline__ void comb(float& m1, float& s1, float m2, float s2) {
  float M = fmaxf(m1, m2);
  float e1 = (s1 > 0.f) ? expf(m1 - M) : 0.f;
  float e2 = (s2 > 0.f) ? expf(m2 - M) : 0.f;
  s1 = s1 * e1 + s2 * e2;
  m1 = M;
}
__device__ __forceinline__ void comb_sl(float& m1, float& s1, float& sl1,
                                        float m2, float s2, float sl2) {
  float M = fmaxf(m1, m2);
  float e1 = (s1 > 0.f) ? expf(m1 - M) : 0.f;
  float e2 = (s2 > 0.f) ? expf(m2 - M) : 0.f;
  s1 = s1 * e1 + s2 * e2;
  sl1 = sl1 * e1 + sl2 * e2;
  m1 = M;
}

// ---------- psi (normalized bubbles) + Gram matrix G = Psi^T Psi ----------
__global__ void k_prep(const float* __restrict__ bub, float* __restrict__ ws) {
  __shared__ float psi[Jc * Dc];
  __shared__ float nrm[Jc];
  int tid = threadIdx.x;
  for (int i = tid; i < Jc * Dc; i += 256) psi[i] = bub[i];
  __syncthreads();
  if (tid < Jc) {
    float s = 0.f;
    for (int d = 0; d < Dc; ++d) { float b = psi[tid * Dc + d]; s += b * b; }
    nrm[tid] = sqrtf(s) + 1e-10f;
  }
  __syncthreads();
  for (int i = tid; i < Jc * Dc; i += 256) {
    float v = psi[i] / nrm[i / Dc];
    psi[i] = v;
    ws[WS_PSI + i] = v;
  }
  __syncthreads();
  for (int i = tid; i < Jc * Jc; i += 256) {
    int r = i / Jc, c = i % Jc;
    float s = 0.f;
    for (int d = 0; d < Dc; ++d) s += psi[r * Dc + d] * psi[c * Dc + d];
    ws[WS_G + i] = s;
  }
}

// ---------- P2T[j][v] = (E[v] . psi_j)^2 ----------
__global__ void k_proj(const float* __restrict__ E, float* __restrict__ ws) {
  __shared__ float4 psi4[Jc][Dc / 4];
  int tid = threadIdx.x;
  for (int i = tid; i < Jc * Dc / 4; i += 256)
    ((float4*)psi4)[i] = ((const float4*)(ws + WS_PSI))[i];
  __syncthreads();
  int v = blockIdx.x * 256 + tid;
  if (v >= Vv) return;
  float acc[Jc];
#pragma unroll
  for (int j = 0; j < Jc; ++j) acc[j] = 0.f;
  const float4* e4 = (const float4*)(E + (size_t)v * Dc);
  for (int d = 0; d < Dc / 4; ++d) {
    float4 e = e4[d];
#pragma unroll
    for (int j = 0; j < Jc; ++j) {
      float4 p = psi4[j][d];
      acc[j] += e.x * p.x + e.y * p.y + e.z * p.z + e.w * p.w;
    }
  }
#pragma unroll
  for (int j = 0; j < Jc; ++j) ws[WS_P2T + (size_t)j * Vv + v] = acc[j] * acc[j];
}

// ---------- sequential recurrence over T=64 steps; emits w[t][24] ----------
__global__ void k_recur(const int* __restrict__ tok, const float* __restrict__ E,
                        const float* __restrict__ bub, const float* __restrict__ pdb,
                        const float* __restrict__ psn, float* __restrict__ ws) {
  __shared__ float mem[Kc * NBc * Dc];
  __shared__ float x[Dc];
  __shared__ float mm[Kc * Dc];
  __shared__ float xm[Kc * Dc];
  __shared__ float sc[Jc];
  __shared__ float wsm[Jc];
  __shared__ float dec[Kc];
  __shared__ float red[8];   // [0..2]=dot(mm,x), [3..5]=|mm|^2, [6]=|x|^2
  int tid = threadIdx.x;
  float db = pdb[0];
  float sens = fabsf(psn[0]);
  for (int i = tid; i < Kc * NBc * Dc; i += 256) mem[i] = 0.f;
  __syncthreads();
  for (int t = 0; t < Tc; ++t) {
    int tk = tok[t];
    if (tid < Dc) x[tid] = E[(size_t)tk * Dc + tid];
    for (int i = tid; i < Kc * Dc; i += 256) {
      int k = i / Dc, d = i % Dc;
      float s = 0.f;
#pragma unroll
      for (int n = 0; n < NBc; ++n) s += mem[(k * NBc + n) * Dc + d];
      mm[i] = s * (1.f / NBc);
    }
    __syncthreads();
    {
      int wv = tid >> 6, ln = tid & 63;
      float a, b = 0.f;
      if (wv < Kc) {
        float m1 = mm[wv * Dc + ln], m2 = mm[wv * Dc + 64 + ln];
        float x1 = x[ln], x2 = x[64 + ln];
        a = m1 * x1 + m2 * x2;
        b = m1 * m1 + m2 * m2;
      } else {
        float x1 = x[ln], x2 = x[64 + ln];
        a = x1 * x1 + x2 * x2;
      }
#pragma unroll
      for (int off = 32; off; off >>= 1) { a += __shfl_down(a, off); b += __shfl_down(b, off); }
      if (ln == 0) { if (wv < Kc) { red[wv] = a; red[3 + wv] = b; } else red[6] = a; }
    }
    __syncthreads();
    if (tid < Kc) {
      float mn = sqrtf(red[3 + tid]) + 1e-10f;
      float xn = sqrtf(red[6]) + 1e-10f;
      float cosv = red[tid] / (xn * mn);
      float nov = (mn > 1e-8f) ? (1.f - cosv) : 1.f;
      dec[tid] = 1.f / (1.f + expf(-(db - sens * nov)));
    }
    __syncthreads();
    for (int i = tid; i < Kc * Dc; i += 256) xm[i] = x[i % Dc] + dec[i / Dc] * mm[i];
    __syncthreads();
    if (tid < Jc * 8) {           // j = tid/8 (24 dots), c = tid%8 covers 16 dims each
      int j = tid >> 3, c = tid & 7;
      int k = j >> 3;
      float s = 0.f;
#pragma unroll
      for (int q = 0; q < 16; ++q) { int d = c * 16 + q; s += bub[j * Dc + d] * xm[k * Dc + d]; }
      s += __shfl_down(s, 4);
      s += __shfl_down(s, 2);
      s += __shfl_down(s, 1);
      if (c == 0) sc[j] = s * (DIVW * INV_SQRT_D);
    }
    __syncthreads();
    if (tid < Kc) {
      float mx = sc[tid * NBc];
#pragma unroll
      for (int n = 1; n < NBc; ++n) mx = fmaxf(mx, sc[tid * NBc + n]);
      float e[NBc]; float ss = 0.f;
#pragma unroll
      for (int n = 0; n < NBc; ++n) { e[n] = expf(sc[tid * NBc + n] - mx); ss += e[n]; }
#pragma unroll
      for (int n = 0; n < NBc; ++n) wsm[tid * NBc + n] = e[n] / ss;
    }
    __syncthreads();
    if (tid < Jc) ws[WS_WALL + (size_t)t * Jc + tid] = wsm[tid];
    for (int i = tid; i < Kc * NBc * Dc; i += 256) {
      int kn = i / Dc, d = i % Dc;
      int k = kn >> 3;
      float de = dec[k];
      float wv2 = wsm[kn];
      float eq = wv2 * xm[k * Dc + d] + (1.f - wv2) * bub[i];
      mem[i] = de * mem[i] + (1.f - de) * eq;
    }
    __syncthreads();
  }
}

// ---------- rho[t] = sum_j (w_j/3) psi_j psi_j^T  (one block per t) ----------
__global__ void k_rho(const float* __restrict__ ws, float* __restrict__ out) {
  int t = blockIdx.x;
  __shared__ float psis[Jc * Dc];
  __shared__ float wsh[Jc];
  int tid = threadIdx.x;
  for (int i = tid; i < Jc * Dc; i += 256) psis[i] = ws[WS_PSI + i];
  if (tid < Jc) wsh[tid] = ws[WS_WALL + (size_t)t * Jc + tid] * (1.f / 3.f);
  __syncthreads();
  int d = tid >> 1, eh = (tid & 1) * 64;
  float4 acc[16];
#pragma unroll
  for (int i = 0; i < 16; ++i) acc[i] = make_float4(0.f, 0.f, 0.f, 0.f);
  for (int j = 0; j < Jc; ++j) {
    float a = wsh[j] * psis[j * Dc + d];
    const float4* pr = (const float4*)&psis[j * Dc + eh];
#pragma unroll
    for (int i = 0; i < 16; ++i) {
      float4 p = pr[i];
      acc[i].x += a * p.x; acc[i].y += a * p.y; acc[i].z += a * p.z; acc[i].w += a * p.w;
    }
  }
  float* o = out + OFF_RHO + (size_t)t * Dc * Dc + (size_t)d * Dc + eh;
#pragma unroll
  for (int i = 0; i < 16; ++i) ((float4*)o)[i] = acc[i];
}

// ---------- S_rho[t]: 24x24 Jacobi, wave-synchronous, compile-time schedule ----------
// One wave (64 threads) per t. Round-robin pairs are an ALU formula of the
// round index; rotations partition the matrix into 144 closed 2x2 blocks
// (rows {p,q} x cols {p',q'}), updated in place. Coefficients shared by
// __shfl (bit-identical in both lanes of a pair). No __syncthreads in the
// loop: single-wave LDS ops execute in order; wave_barrier() fences the
// compiler only.
__global__ void k_eig(const float* __restrict__ ws, float* __restrict__ out) {
  int t = blockIdx.x;
  __shared__ float A[Jc * 25];         // stride 25: bank-decorrelated
  int lane = threadIdx.x;              // 64 threads = 1 wave
  for (int i = lane; i < Jc * Jc; i += 64) {
    int r = i / Jc, c = i % Jc;
    A[r * 25 + c] = ws[WS_G + i] *
                    sqrtf(ws[WS_WALL + (size_t)t * Jc + r] * ws[WS_WALL + (size_t)t * Jc + c]) *
                    (1.f / 3.f);
  }
  __syncthreads();                     // once: cover the init
  for (int sweep = 0; sweep < 7; ++sweep) {
    for (int rr = 0; rr < 23; ++rr) {
      // --- rotation params: lane j<24 handles its pair (canonical lo<hi order)
      float cv = 1.f, sv = 0.f;
      if (lane < Jc) {
        int j = lane;
        int m = (j == 23) ? rr : ((j == rr) ? 23 : (2 * rr + 23 - j) % 23);
        int lo = min(j, m), hi = max(j, m);
        float ajj = A[j * 25 + j];
        float alh = A[lo * 25 + hi];
        float amm = __shfl(ajj, m);
        float app = (j == lo) ? ajj : amm;
        float aqq = (j == lo) ? amm : ajj;
        if (fabsf(alh) > 1e-20f) {
          float th = (aqq - app) / (2.f * alh);
          float tt = 1.f / (fabsf(th) + sqrtf(1.f + th * th));
          if (th < 0.f) tt = -tt;
          cv = 1.f / sqrtf(1.f + tt * tt);
          sv = tt * cv;
        }
      }
      __builtin_amdgcn_wave_barrier();
      // --- update 144 closed 2x2 blocks, 64 lanes, in place
#pragma unroll
      for (int it = 0; it < 3; ++it) {
        int b = lane + 64 * it;
        int bb = (b < 144) ? b : 143;        // clamp so shuffles stay well-defined
        int pi = bb / 12, pj = bb % 12;
        int p0, q0, p1, q1;
        if (pi == 0) { p0 = rr; q0 = 23; }
        else { int a = (rr + pi) % 23, b2 = (rr + 23 - pi) % 23; p0 = min(a, b2); q0 = max(a, b2); }
        if (pj == 0) { p1 = rr; q1 = 23; }
        else { int a = (rr + pj) % 23, b2 = (rr + 23 - pj) % 23; p1 = min(a, b2); q1 = max(a, b2); }
        float ci = __shfl(cv, p0), si = __shfl(sv, p0);
        float cj = __shfl(cv, p1), sj = __shfl(sv, p1);
        if (b < 144) {
          float m00 = A[p0 * 25 + p1], m01 = A[p0 * 25 + q1];
          float m10 = A[q0 * 25 + p1], m11 = A[q0 * 25 + q1];
          // rows: lo' = c*lo - s*hi ; hi' = s*lo + c*hi
          float r00 = ci * m00 - si * m10, r01 = ci * m01 - si * m11;
          float r10 = si * m00 + ci * m10, r11 = si * m01 + ci * m11;
          // cols: same transform
          float o00 = cj * r00 - sj * r01, o01 = sj * r00 + cj * r01;
          float o10 = cj * r10 - sj * r11, o11 = sj * r10 + cj * r11;
          A[p0 * 25 + p1] = o00; A[p0 * 25 + q1] = o01;
          A[q0 * 25 + p1] = o10; A[q0 * 25 + q1] = o11;
        }
      }
      __builtin_amdgcn_wave_barrier();
    }
  }
  // entropy of {diag(A)} U {104 x 1e-12 clipped zeros}
  float lam = 0.f;
  if (lane < Jc) lam = fmaxf(A[lane * 25 + lane], 1e-12f);
  float tot = lam;
#pragma unroll
  for (int off = 32; off; off >>= 1) tot += __shfl_down(tot, off);
  tot = __shfl(tot, 0);
  tot += (float)(Dc - Jc) * 1e-12f;
  float term = 0.f;
  if (lane < Jc) { float p = lam / tot; term = p * logf(p); }
#pragma unroll
  for (int off = 32; off; off >>= 1) term += __shfl_down(term, off);
  if (lane == 0) {
    float pe = 1e-12f / tot;
    out[OFF_S + t] = -(term + (float)(Dc - Jc) * pe * logf(pe));
  }
}

// ---------- logits (stored into d_out prob regions) + online-softmax partials ----------
__global__ void k_logits(float* __restrict__ ws, float* __restrict__ out) {
  int ch = blockIdx.x, t = blockIdx.y, tid = threadIdx.x;
  __shared__ float wsh[Jc];
  __shared__ float rm[4][4], rs[4][4], rsl2[4];
  if (tid < Jc) wsh[tid] = ws[WS_WALL + (size_t)t * Jc + tid];
  __syncthreads();
  float m[4] = {-INFINITY, -INFINITY, -INFINITY, -INFINITY};
  float s[4] = {0.f, 0.f, 0.f, 0.f};
  float sl = 0.f;
  const float* p2 = ws + WS_P2T;
  for (int r = 0; r < 4; ++r) {
    int v = ch * CHV + r * 256 + tid;
    if (v >= Vv) break;
    float l0 = 0.f, l1 = 0.f, l2 = 0.f;
#pragma unroll
    for (int n = 0; n < NBc; ++n) {
      l0 += wsh[n]      * p2[(size_t)n * Vv + v];
      l1 += wsh[8 + n]  * p2[(size_t)(8 + n) * Vv + v];
      l2 += wsh[16 + n] * p2[(size_t)(16 + n) * Vv + v];
    }
    float l[4] = { l0, l1, l2, (l0 + l1 + l2) * (1.f / 3.f) };
    out[OFF_TOK + (size_t)t * Vv + v] = l[3];
    out[OFF_PF + ((size_t)t * Kc + 0) * Vv + v] = l0;
    out[OFF_PF + ((size_t)t * Kc + 1) * Vv + v] = l1;
    out[OFF_PF + ((size_t)t * Kc + 2) * Vv + v] = l2;
#pragma unroll
    for (int d = 0; d < 4; ++d) {
      float li = l[d];
      if (li > m[d]) {
        float e = expf(m[d] - li);       // 0 when m = -inf
        s[d] = s[d] * e + 1.f;
        if (d == 3) sl = sl * e + li;
        m[d] = li;
      } else {
        float e = expf(li - m[d]);
        s[d] += e;
        if (d == 3) sl += e * li;
      }
    }
  }
  // wave reduce
#pragma unroll
  for (int off = 32; off; off >>= 1) {
#pragma unroll
    for (int d = 0; d < 3; ++d) {
      float om = __shfl_down(m[d], off);
      float os = __shfl_down(s[d], off);
      comb(m[d], s[d], om, os);
    }
    float om = __shfl_down(m[3], off);
    float os = __shfl_down(s[3], off);
    float osl = __shfl_down(sl, off);
    comb_sl(m[3], s[3], sl, om, os, osl);
  }
  int wv = tid >> 6, ln = tid & 63;
  if (ln == 0) {
#pragma unroll
    for (int d = 0; d < 4; ++d) { rm[wv][d] = m[d]; rs[wv][d] = s[d]; }
    rsl2[wv] = sl;
  }
  __syncthreads();
  if (tid == 0) {
    float* part = ws + WS_PART + ((size_t)t * NCH + ch) * 9;
    for (int d = 0; d < 3; ++d) {
      float M = rm[0][d], S = rs[0][d];
      for (int w2 = 1; w2 < 4; ++w2) comb(M, S, rm[w2][d], rs[w2][d]);
      part[d] = M; part[4 + d] = S;
    }
    float M = rm[0][3], S = rs[0][3], SL = rsl2[0];
    for (int w2 = 1; w2 < 4; ++w2) comb_sl(M, S, SL, rm[w2][3], rs[w2][3], rsl2[w2]);
    part[3] = M; part[7] = S; part[8] = SL;
  }
}

// ---------- merge chunk partials -> logZ[t][4]; H, F ----------
__global__ void k_reduce(float* __restrict__ ws, float* __restrict__ out) {
  int t = blockIdx.x, tid = threadIdx.x;
  if (tid < 4) {
    float M = -INFINITY, S = 0.f, SL = 0.f;
    for (int ch = 0; ch < NCH; ++ch) {
      const float* p = ws + WS_PART + ((size_t)t * NCH + ch) * 9;
      if (tid == 3) comb_sl(M, S, SL, p[3], p[7], p[8]);
      else          comb(M, S, p[tid], p[4 + tid]);
    }
    float lz = M + logf(S);
    ws[WS_LOGZ + (size_t)t * 4 + tid] = lz;
    if (tid == 3) {
      float H = lz - SL / S;
      float Srho = out[OFF_S + t];
      out[OFF_H + t] = H;
      out[OFF_F + t] = H - Srho;
    }
  }
}

// ---------- in-place logits -> probs ----------
__global__ void k_norm(const float* __restrict__ ws, float* __restrict__ out, int foam) {
  int row = blockIdx.y, ch = blockIdx.x, tid = threadIdx.x;
  size_t base; int lzi;
  if (foam) { int t = row / Kc, k = row % Kc; base = OFF_PF + (size_t)row * Vv; lzi = t * 4 + k; }
  else { base = OFF_TOK + (size_t)row * Vv; lzi = row * 4 + 3; }
  float lz = ws[WS_LOGZ + lzi];
  for (int r = 0; r < 4; ++r) {
    int v = ch * CHV + r * 256 + tid;
    if (v < Vv) out[base + v] = expf(out[base + v] - lz);
  }
}

extern "C" void kernel_launch(void* const* d_in, const int* in_sizes, int n_in,
                              void* d_out, int out_size, void* d_ws, size_t ws_size,
                              hipStream_t stream) {
  const int*   tokens = (const int*)d_in[0];
  const float* E      = (const float*)d_in[1];
  const float* bub    = (const float*)d_in[2];
  const float* pdb    = (const float*)d_in[3];
  const float* psn    = (const float*)d_in[4];
  float* out = (float*)d_out;
  float* ws  = (float*)d_ws;

  k_prep<<<1, 256, 0, stream>>>(bub, ws);
  k_proj<<<(Vv + 255) / 256, 256, 0, stream>>>(E, ws);
  k_recur<<<1, 256, 0, stream>>>(tokens, E, bub, pdb, psn, ws);
  k_rho<<<Tc, 256, 0, stream>>>(ws, out);
  k_eig<<<Tc, 64, 0, stream>>>(ws, out);
  k_logits<<<dim3(NCH, Tc), 256, 0, stream>>>(ws, out);
  k_reduce<<<Tc, 64, 0, stream>>>(ws, out);
  k_norm<<<dim3(NCH, Tc), 256, 0, stream>>>(ws, out, 0);
  k_norm<<<dim3(NCH, Tc * Kc), 256, 0, stream>>>(ws, out, 1);
}

// Round 3
// 501.284 us; speedup vs baseline: 1.2794x; 1.0935x over previous
//
#include <hip/hip_runtime.h>
#include <math.h>

namespace {
constexpr int Vv  = 50257;
constexpr int Dc  = 128;
constexpr int Kc  = 3;
constexpr int NBc = 8;
constexpr int Jc  = 24;      // K*NB
constexpr int Tc  = 64;
constexpr int CHV = 1024;                      // vocab elems per block chunk
constexpr int NCH = (Vv + CHV - 1) / CHV;      // 50
constexpr float INV_SQRT_D = 0.08838834764831845f;
constexpr float DIVW = 2.0f;

// ws layout (float offsets)
constexpr size_t WS_PSI  = 0;        // 24*128
constexpr size_t WS_G    = 4096;     // 24*24 (psi gram)
constexpr size_t WS_BB   = 5120;     // 24*24 (raw bubble gram)
constexpr size_t WS_XN   = 6144;     // 64   |x_t|^2
constexpr size_t WS_BX   = 6400;     // 64*24 bub_j . x_t
constexpr size_t WS_WALL = 8192;     // 64*24
constexpr size_t WS_PART = 12288;    // 64*50*9 = 28800
constexpr size_t WS_LOGZ = 45056;    // 64*4
constexpr size_t WS_P2T  = 65536;    // 24*V  (transposed: [j][v] for coalescing)

// out layout (float offsets), reference return order
constexpr size_t OFF_TOK = 0;
constexpr size_t OFF_RHO = (size_t)Tc * Vv;
constexpr size_t OFF_S   = OFF_RHO + (size_t)Tc * Dc * Dc;
constexpr size_t OFF_H   = OFF_S + Tc;
constexpr size_t OFF_F   = OFF_H + Tc;
constexpr size_t OFF_PF  = OFF_F + Tc;
}

__device__ __forceinline__ float wsum64(float v) {
#pragma unroll
  for (int m = 1; m < 64; m <<= 1) v += __shfl_xor(v, m);
  return v;
}

// online-softmax merge helpers
__device__ __forceinline__ void comb(float& m1, float& s1, float m2, float s2) {
  float M = fmaxf(m1, m2);
  float e1 = (s1 > 0.f) ? expf(m1 - M) : 0.f;
  float e2 = (s2 > 0.f) ? expf(m2 - M) : 0.f;
  s1 = s1 * e1 + s2 * e2;
  m1 = M;
}
__device__ __forceinline__ void comb_sl(float& m1, float& s1, float& sl1,
                                        float m2, float s2, float sl2) {
  float M = fmaxf(m1, m2);
  float e1 = (s1 > 0.f) ? expf(m1 - M) : 0.f;
  float e2 = (s2 > 0.f) ? expf(m2 - M) : 0.f;
  s1 = s1 * e1 + s2 * e2;
  sl1 = sl1 * e1 + sl2 * e2;
  m1 = M;
}

// ---------- psi + psi-Gram G + raw bubble Gram BB ----------
__global__ void k_prep(const float* __restrict__ bub, float* __restrict__ ws) {
  __shared__ float braw[Jc * Dc];
  __shared__ float psi[Jc * Dc];
  __shared__ float nrm[Jc];
  int tid = threadIdx.x;
  for (int i = tid; i < Jc * Dc; i += 256) braw[i] = bub[i];
  __syncthreads();
  if (tid < Jc) {
    float s = 0.f;
    for (int d = 0; d < Dc; ++d) { float b = braw[tid * Dc + d]; s += b * b; }
    nrm[tid] = sqrtf(s) + 1e-10f;
  }
  __syncthreads();
  for (int i = tid; i < Jc * Dc; i += 256) {
    float v = braw[i] / nrm[i / Dc];
    psi[i] = v;
    ws[WS_PSI + i] = v;
  }
  __syncthreads();
  for (int i = tid; i < Jc * Jc; i += 256) {
    int r = i / Jc, c = i % Jc;
    float g = 0.f, b = 0.f;
    for (int d = 0; d < Dc; ++d) {
      g += psi[r * Dc + d] * psi[c * Dc + d];
      b += braw[r * Dc + d] * braw[c * Dc + d];
    }
    ws[WS_G + i] = g;
    ws[WS_BB + i] = b;
  }
}

// ---------- per-token precompute: BX[t][j] = bub_j . E[tok_t], XN[t] = |x|^2 ----------
__global__ void k_tok(const int* __restrict__ tok, const float* __restrict__ E,
                      const float* __restrict__ bub, float* __restrict__ ws) {
  int t = blockIdx.x, lane = threadIdx.x;   // 64 threads = 1 wave
  int tk = tok[t];
  float eA = E[(size_t)tk * Dc + lane];
  float eB = E[(size_t)tk * Dc + 64 + lane];
  float xn = wsum64(eA * eA + eB * eB);
  if (lane == 0) ws[WS_XN + t] = xn;
  float p[Jc];
#pragma unroll
  for (int j = 0; j < Jc; ++j)
    p[j] = bub[j * Dc + lane] * eA + bub[j * Dc + 64 + lane] * eB;
#pragma unroll
  for (int j = 0; j < Jc; ++j) p[j] = wsum64(p[j]);
  if (lane == 0) {
#pragma unroll
    for (int j = 0; j < Jc; ++j) ws[WS_BX + (size_t)t * Jc + j] = p[j];
  }
}

// ---------- sequential recurrence, single wave, register-resident ----------
// State: mm_k (bubble-mean vectors, dims across lanes: lane holds d and d+64)
// and BM[j][k] = bub_j . mm_k (lane j<24). Closed-form recurrences (sum_n w=1):
//   mm'_k = dec*mm_k + (1-dec)/8 * (xm_k + sum_n (1-w_kn) bub_kn)
//   BM'   = dec*BM   + (1-dec)/8 * (bub_j.xm_k + sum_n (1-w_kn) BB[j][kn])
//   bub_j.xm_k = BX[t][j] + dec*BM[j][k]
// Scores need NO cross-lane reduction; only mm.x and |mm|^2 butterfly (6).
__global__ void k_recur(const int* __restrict__ tok, const float* __restrict__ E,
                        const float* __restrict__ bub, const float* __restrict__ pdb,
                        const float* __restrict__ psn, float* __restrict__ ws) {
  __shared__ float sBX[Tc * Jc];
  __shared__ float sXN[Tc];
  int lane = threadIdx.x;                 // 64 threads = 1 wave
  for (int i = lane; i < Tc * Jc; i += 64) sBX[i] = ws[WS_BX + i];
  if (lane < Tc) sXN[lane] = ws[WS_XN + lane];
  float db = pdb[0];
  float sens = fabsf(psn[0]);
  int tokv = tok[lane];
  // raw bubbles, dims across lanes
  float bubA[Jc], bubB[Jc];
#pragma unroll
  for (int j = 0; j < Jc; ++j) {
    bubA[j] = bub[j * Dc + lane];
    bubB[j] = bub[j * Dc + 64 + lane];
  }
  int jme = (lane < Jc) ? lane : (Jc - 1);
  int kme = jme >> 3;
  // BB row for this lane's j
  float BBrow[Jc];
#pragma unroll
  for (int j = 0; j < Jc; ++j) BBrow[j] = ws[WS_BB + (size_t)jme * Jc + j];
  __syncthreads();
  // state
  float mmA[Kc] = {0.f, 0.f, 0.f}, mmB[Kc] = {0.f, 0.f, 0.f};
  float BMv[Kc] = {0.f, 0.f, 0.f};
  // prefetch x for t=0
  int tk0 = __shfl(tokv, 0);
  float xA = E[(size_t)tk0 * Dc + lane];
  float xB = E[(size_t)tk0 * Dc + 64 + lane];
  for (int t = 0; t < Tc; ++t) {
    // prefetch next token's embedding row (off critical path)
    float nxA = 0.f, nxB = 0.f;
    if (t + 1 < Tc) {
      int nk = __shfl(tokv, t + 1);
      nxA = E[(size_t)nk * Dc + lane];
      nxB = E[(size_t)nk * Dc + 64 + lane];
    }
    // mm.x and |mm|^2 (butterfly over dims)
    float dk[Kc], nk2[Kc];
#pragma unroll
    for (int k = 0; k < Kc; ++k) {
      dk[k]  = wsum64(mmA[k] * xA + mmB[k] * xB);
      nk2[k] = wsum64(mmA[k] * mmA[k] + mmB[k] * mmB[k]);
    }
    float xn = sqrtf(sXN[t]) + 1e-10f;
    float dec[Kc], xmA[Kc], xmB[Kc];
#pragma unroll
    for (int k = 0; k < Kc; ++k) {
      float mn = sqrtf(nk2[k]) + 1e-10f;
      float cosv = dk[k] / (xn * mn);
      float nov = (mn > 1e-8f) ? (1.f - cosv) : 1.f;
      dec[k] = 1.f / (1.f + expf(-(db - sens * nov)));
      xmA[k] = xA + dec[k] * mmA[k];
      xmB[k] = xB + dec[k] * mmB[k];
    }
    // scores + softmax, lane j<24 owns bubble j (octet = foam k)
    float bxj = sBX[t * Jc + jme];
    float decS = (kme == 0) ? dec[0] : ((kme == 1) ? dec[1] : dec[2]);
    float sc = (bxj + decS * BMv[kme]) * (DIVW * INV_SQRT_D);
    float mx = sc;
    mx = fmaxf(mx, __shfl_xor(mx, 1));
    mx = fmaxf(mx, __shfl_xor(mx, 2));
    mx = fmaxf(mx, __shfl_xor(mx, 4));
    float e = expf(sc - mx);
    float ss = e;
    ss += __shfl_xor(ss, 1);
    ss += __shfl_xor(ss, 2);
    ss += __shfl_xor(ss, 4);
    float w = e / ss;
    if (lane < Jc) ws[WS_WALL + (size_t)t * Jc + lane] = w;
    // broadcast all 24 weights (readlane)
    float wj[Jc];
#pragma unroll
    for (int j = 0; j < Jc; ++j) wj[j] = __shfl(w, j);
    // mm update: mm' = dec*mm + (1-dec)/8*(xm + sum_n (1-w) bub)
#pragma unroll
    for (int k = 0; k < Kc; ++k) {
      float accA = 0.f, accB = 0.f;
#pragma unroll
      for (int n = 0; n < NBc; ++n) {
        float om = 1.f - wj[k * NBc + n];
        accA += om * bubA[k * NBc + n];
        accB += om * bubB[k * NBc + n];
      }
      float od8 = (1.f - dec[k]) * 0.125f;
      mmA[k] = dec[k] * mmA[k] + od8 * (xmA[k] + accA);
      mmB[k] = dec[k] * mmB[k] + od8 * (xmB[k] + accB);
    }
    // BM update (per-lane j): BM' = dec*BM + (1-dec)/8*((BX + dec*BM) + sum_n (1-w) BB)
#pragma unroll
    for (int k = 0; k < Kc; ++k) {
      float bxm = bxj + dec[k] * BMv[k];
      float s2 = 0.f;
#pragma unroll
      for (int n = 0; n < NBc; ++n) s2 += (1.f - wj[k * NBc + n]) * BBrow[k * NBc + n];
      BMv[k] = dec[k] * BMv[k] + (1.f - dec[k]) * 0.125f * (bxm + s2);
    }
    xA = nxA; xB = nxB;
  }
}

// ---------- P2T[j][v] = (E[v] . psi_j)^2 ----------
__global__ void k_proj(const float* __restrict__ E, float* __restrict__ ws) {
  __shared__ float4 psi4[Jc][Dc / 4];
  int tid = threadIdx.x;
  for (int i = tid; i < Jc * Dc / 4; i += 256)
    ((float4*)psi4)[i] = ((const float4*)(ws + WS_PSI))[i];
  __syncthreads();
  int v = blockIdx.x * 256 + tid;
  if (v >= Vv) return;
  float acc[Jc];
#pragma unroll
  for (int j = 0; j < Jc; ++j) acc[j] = 0.f;
  const float4* e4 = (const float4*)(E + (size_t)v * Dc);
  for (int d = 0; d < Dc / 4; ++d) {
    float4 e = e4[d];
#pragma unroll
    for (int j = 0; j < Jc; ++j) {
      float4 p = psi4[j][d];
      acc[j] += e.x * p.x + e.y * p.y + e.z * p.z + e.w * p.w;
    }
  }
#pragma unroll
  for (int j = 0; j < Jc; ++j) ws[WS_P2T + (size_t)j * Vv + v] = acc[j] * acc[j];
}

// ---------- rho[t] = sum_j (w_j/3) psi_j psi_j^T  (one block per t) ----------
__global__ void k_rho(const float* __restrict__ ws, float* __restrict__ out) {
  int t = blockIdx.x;
  __shared__ float psis[Jc * Dc];
  __shared__ float wsh[Jc];
  int tid = threadIdx.x;
  for (int i = tid; i < Jc * Dc; i += 256) psis[i] = ws[WS_PSI + i];
  if (tid < Jc) wsh[tid] = ws[WS_WALL + (size_t)t * Jc + tid] * (1.f / 3.f);
  __syncthreads();
  int d = tid >> 1, eh = (tid & 1) * 64;
  float4 acc[16];
#pragma unroll
  for (int i = 0; i < 16; ++i) acc[i] = make_float4(0.f, 0.f, 0.f, 0.f);
  for (int j = 0; j < Jc; ++j) {
    float a = wsh[j] * psis[j * Dc + d];
    const float4* pr = (const float4*)&psis[j * Dc + eh];
#pragma unroll
    for (int i = 0; i < 16; ++i) {
      float4 p = pr[i];
      acc[i].x += a * p.x; acc[i].y += a * p.y; acc[i].z += a * p.z; acc[i].w += a * p.w;
    }
  }
  float* o = out + OFF_RHO + (size_t)t * Dc * Dc + (size_t)d * Dc + eh;
#pragma unroll
  for (int i = 0; i < 16; ++i) ((float4*)o)[i] = acc[i];
}

// ---------- S_rho[t]: 24x24 Jacobi, wave-synchronous, compile-time schedule ----------
__global__ void k_eig(const float* __restrict__ ws, float* __restrict__ out) {
  int t = blockIdx.x;
  __shared__ float A[Jc * 25];         // stride 25: bank-decorrelated
  int lane = threadIdx.x;              // 64 threads = 1 wave
  for (int i = lane; i < Jc * Jc; i += 64) {
    int r = i / Jc, c = i % Jc;
    A[r * 25 + c] = ws[WS_G + i] *
                    sqrtf(ws[WS_WALL + (size_t)t * Jc + r] * ws[WS_WALL + (size_t)t * Jc + c]) *
                    (1.f / 3.f);
  }
  __syncthreads();
  for (int sweep = 0; sweep < 7; ++sweep) {
    for (int rr = 0; rr < 23; ++rr) {
      float cv = 1.f, sv = 0.f;
      if (lane < Jc) {
        int j = lane;
        int m = (j == 23) ? rr : ((j == rr) ? 23 : (2 * rr + 23 - j) % 23);
        int lo = min(j, m), hi = max(j, m);
        float ajj = A[j * 25 + j];
        float alh = A[lo * 25 + hi];
        float amm = __shfl(ajj, m);
        float app = (j == lo) ? ajj : amm;
        float aqq = (j == lo) ? amm : ajj;
        if (fabsf(alh) > 1e-20f) {
          float th = (aqq - app) / (2.f * alh);
          float tt = 1.f / (fabsf(th) + sqrtf(1.f + th * th));
          if (th < 0.f) tt = -tt;
          cv = 1.f / sqrtf(1.f + tt * tt);
          sv = tt * cv;
        }
      }
      __builtin_amdgcn_wave_barrier();
#pragma unroll
      for (int it = 0; it < 3; ++it) {
        int b = lane + 64 * it;
        int bb = (b < 144) ? b : 143;
        int pi = bb / 12, pj = bb % 12;
        int p0, q0, p1, q1;
        if (pi == 0) { p0 = rr; q0 = 23; }
        else { int a = (rr + pi) % 23, b2 = (rr + 23 - pi) % 23; p0 = min(a, b2); q0 = max(a, b2); }
        if (pj == 0) { p1 = rr; q1 = 23; }
        else { int a = (rr + pj) % 23, b2 = (rr + 23 - pj) % 23; p1 = min(a, b2); q1 = max(a, b2); }
        float ci = __shfl(cv, p0), si = __shfl(sv, p0);
        float cj = __shfl(cv, p1), sj = __shfl(sv, p1);
        if (b < 144) {
          float m00 = A[p0 * 25 + p1], m01 = A[p0 * 25 + q1];
          float m10 = A[q0 * 25 + p1], m11 = A[q0 * 25 + q1];
          float r00 = ci * m00 - si * m10, r01 = ci * m01 - si * m11;
          float r10 = si * m00 + ci * m10, r11 = si * m01 + ci * m11;
          float o00 = cj * r00 - sj * r01, o01 = sj * r00 + cj * r01;
          float o10 = cj * r10 - sj * r11, o11 = sj * r10 + cj * r11;
          A[p0 * 25 + p1] = o00; A[p0 * 25 + q1] = o01;
          A[q0 * 25 + p1] = o10; A[q0 * 25 + q1] = o11;
        }
      }
      __builtin_amdgcn_wave_barrier();
    }
  }
  float lam = 0.f;
  if (lane < Jc) lam = fmaxf(A[lane * 25 + lane], 1e-12f);
  float tot = lam;
#pragma unroll
  for (int off = 32; off; off >>= 1) tot += __shfl_down(tot, off);
  tot = __shfl(tot, 0);
  tot += (float)(Dc - Jc) * 1e-12f;
  float term = 0.f;
  if (lane < Jc) { float p = lam / tot; term = p * logf(p); }
#pragma unroll
  for (int off = 32; off; off >>= 1) term += __shfl_down(term, off);
  if (lane == 0) {
    float pe = 1e-12f / tot;
    out[OFF_S + t] = -(term + (float)(Dc - Jc) * pe * logf(pe));
  }
}

// ---------- logits (stored into d_out prob regions) + online-softmax partials ----------
__global__ void k_logits(float* __restrict__ ws, float* __restrict__ out) {
  int ch = blockIdx.x, t = blockIdx.y, tid = threadIdx.x;
  __shared__ float wsh[Jc];
  __shared__ float rm[4][4], rs[4][4], rsl2[4];
  if (tid < Jc) wsh[tid] = ws[WS_WALL + (size_t)t * Jc + tid];
  __syncthreads();
  float m[4] = {-INFINITY, -INFINITY, -INFINITY, -INFINITY};
  float s[4] = {0.f, 0.f, 0.f, 0.f};
  float sl = 0.f;
  const float* p2 = ws + WS_P2T;
  for (int r = 0; r < 4; ++r) {
    int v = ch * CHV + r * 256 + tid;
    if (v >= Vv) break;
    float l0 = 0.f, l1 = 0.f, l2 = 0.f;
#pragma unroll
    for (int n = 0; n < NBc; ++n) {
      l0 += wsh[n]      * p2[(size_t)n * Vv + v];
      l1 += wsh[8 + n]  * p2[(size_t)(8 + n) * Vv + v];
      l2 += wsh[16 + n] * p2[(size_t)(16 + n) * Vv + v];
    }
    float l[4] = { l0, l1, l2, (l0 + l1 + l2) * (1.f / 3.f) };
    out[OFF_TOK + (size_t)t * Vv + v] = l[3];
    out[OFF_PF + ((size_t)t * Kc + 0) * Vv + v] = l0;
    out[OFF_PF + ((size_t)t * Kc + 1) * Vv + v] = l1;
    out[OFF_PF + ((size_t)t * Kc + 2) * Vv + v] = l2;
#pragma unroll
    for (int d = 0; d < 4; ++d) {
      float li = l[d];
      if (li > m[d]) {
        float e = expf(m[d] - li);
        s[d] = s[d] * e + 1.f;
        if (d == 3) sl = sl * e + li;
        m[d] = li;
      } else {
        float e = expf(li - m[d]);
        s[d] += e;
        if (d == 3) sl += e * li;
      }
    }
  }
#pragma unroll
  for (int off = 32; off; off >>= 1) {
#pragma unroll
    for (int d = 0; d < 3; ++d) {
      float om = __shfl_down(m[d], off);
      float os = __shfl_down(s[d], off);
      comb(m[d], s[d], om, os);
    }
    float om = __shfl_down(m[3], off);
    float os = __shfl_down(s[3], off);
    float osl = __shfl_down(sl, off);
    comb_sl(m[3], s[3], sl, om, os, osl);
  }
  int wv = tid >> 6, ln = tid & 63;
  if (ln == 0) {
#pragma unroll
    for (int d = 0; d < 4; ++d) { rm[wv][d] = m[d]; rs[wv][d] = s[d]; }
    rsl2[wv] = sl;
  }
  __syncthreads();
  if (tid == 0) {
    float* part = ws + WS_PART + ((size_t)t * NCH + ch) * 9;
    for (int d = 0; d < 3; ++d) {
      float M = rm[0][d], S = rs[0][d];
      for (int w2 = 1; w2 < 4; ++w2) comb(M, S, rm[w2][d], rs[w2][d]);
      part[d] = M; part[4 + d] = S;
    }
    float M = rm[0][3], S = rs[0][3], SL = rsl2[0];
    for (int w2 = 1; w2 < 4; ++w2) comb_sl(M, S, SL, rm[w2][3], rs[w2][3], rsl2[w2]);
    part[3] = M; part[7] = S; part[8] = SL;
  }
}

// ---------- merge chunk partials -> logZ[t][4]; H, F ----------
__global__ void k_reduce(float* __restrict__ ws, float* __restrict__ out) {
  int t = blockIdx.x, tid = threadIdx.x;
  if (tid < 4) {
    float M = -INFINITY, S = 0.f, SL = 0.f;
    for (int ch = 0; ch < NCH; ++ch) {
      const float* p = ws + WS_PART + ((size_t)t * NCH + ch) * 9;
      if (tid == 3) comb_sl(M, S, SL, p[3], p[7], p[8]);
      else          comb(M, S, p[tid], p[4 + tid]);
    }
    float lz = M + logf(S);
    ws[WS_LOGZ + (size_t)t * 4 + tid] = lz;
    if (tid == 3) {
      float H = lz - SL / S;
      float Srho = out[OFF_S + t];
      out[OFF_H + t] = H;
      out[OFF_F + t] = H - Srho;
    }
  }
}

// ---------- in-place logits -> probs ----------
__global__ void k_norm(const float* __restrict__ ws, float* __restrict__ out, int foam) {
  int row = blockIdx.y, ch = blockIdx.x, tid = threadIdx.x;
  size_t base; int lzi;
  if (foam) { int t = row / Kc, k = row % Kc; base = OFF_PF + (size_t)row * Vv; lzi = t * 4 + k; }
  else { base = OFF_TOK + (size_t)row * Vv; lzi = row * 4 + 3; }
  float lz = ws[WS_LOGZ + lzi];
  for (int r = 0; r < 4; ++r) {
    int v = ch * CHV + r * 256 + tid;
    if (v < Vv) out[base + v] = expf(out[base + v] - lz);
  }
}

extern "C" void kernel_launch(void* const* d_in, const int* in_sizes, int n_in,
                              void* d_out, int out_size, void* d_ws, size_t ws_size,
                              hipStream_t stream) {
  const int*   tokens = (const int*)d_in[0];
  const float* E      = (const float*)d_in[1];
  const float* bub    = (const float*)d_in[2];
  const float* pdb    = (const float*)d_in[3];
  const float* psn    = (const float*)d_in[4];
  float* out = (float*)d_out;
  float* ws  = (float*)d_ws;

  k_prep<<<1, 256, 0, stream>>>(bub, ws);
  k_proj<<<(Vv + 255) / 256, 256, 0, stream>>>(E, ws);
  k_tok<<<Tc, 64, 0, stream>>>(tokens, E, bub, ws);
  k_recur<<<1, 64, 0, stream>>>(tokens, E, bub, pdb, psn, ws);
  k_rho<<<Tc, 256, 0, stream>>>(ws, out);
  k_eig<<<Tc, 64, 0, stream>>>(ws, out);
  k_logits<<<dim3(NCH, Tc), 256, 0, stream>>>(ws, out);
  k_reduce<<<Tc, 64, 0, stream>>>(ws, out);
  k_norm<<<dim3(NCH, Tc), 256, 0, stream>>>(ws, out, 0);
  k_norm<<<dim3(NCH, Tc * Kc), 256, 0, stream>>>(ws, out, 1);
}